// Round 4
// baseline (237.790 us; speedup 1.0000x reference)
//
#include <hip/hip_runtime.h>

// Problem constants (fixed by the reference): N=16384 rows, K=64 clusters, F=2048 features.
#define NROWS 16384
#define KC 64
#define FDIM 2048
#define F4 (FDIM / 4)   // 512 float4 per row
#define ALPHA 1.0f
#define GAMMA 1.0f
#define ROWS 16                  // rows per k_main row-group
#define HB 256                   // histogram blocks (NROWS/64 rows each)
#define ROWS_PER_HB 64           // rows per histogram/scatter block

typedef float f32x4 __attribute__((ext_vector_type(4)));

// ---------------------------------------------------------------------------
// K1: ballot-based argmax of one-hot labels + per-block LDS histogram.
// ---------------------------------------------------------------------------
__global__ __launch_bounds__(256) void k_argmax_hist(
    const float* __restrict__ labels, int* __restrict__ idx,
    int* __restrict__ blockHist) {
    __shared__ int hist[KC];
    int t = threadIdx.x, w = t >> 6, lane = t & 63;
    if (t < KC) hist[t] = 0;
    __syncthreads();
    int rowbase = blockIdx.x * ROWS_PER_HB + w * 16;
    #pragma unroll
    for (int r0 = 0; r0 < 16; r0 += 4) {
        float v0 = labels[(rowbase + r0 + 0) * KC + lane];
        float v1 = labels[(rowbase + r0 + 1) * KC + lane];
        float v2 = labels[(rowbase + r0 + 2) * KC + lane];
        float v3 = labels[(rowbase + r0 + 3) * KC + lane];
        unsigned long long m0 = __ballot(v0 > 0.5f);
        unsigned long long m1 = __ballot(v1 > 0.5f);
        unsigned long long m2 = __ballot(v2 > 0.5f);
        unsigned long long m3 = __ballot(v3 > 0.5f);
        if (lane == 0) {
            int k0 = __ffsll(m0) - 1;
            int k1 = __ffsll(m1) - 1;
            int k2 = __ffsll(m2) - 1;
            int k3 = __ffsll(m3) - 1;
            idx[rowbase + r0 + 0] = k0;
            idx[rowbase + r0 + 1] = k1;
            idx[rowbase + r0 + 2] = k2;
            idx[rowbase + r0 + 3] = k3;
            atomicAdd(&hist[k0], 1);
            atomicAdd(&hist[k1], 1);
            atomicAdd(&hist[k2], 1);
            atomicAdd(&hist[k3], 1);
        }
    }
    __syncthreads();
    if (t < KC) blockHist[blockIdx.x * KC + t] = hist[t];
}

// ---------------------------------------------------------------------------
// K2: parallel prefix. 256 threads = 4 chunks x 64 k. Two passes over the
// 64 KB blockHist (L2-resident).
// ---------------------------------------------------------------------------
__global__ __launch_bounds__(256) void k_prefix(
    const int* __restrict__ blockHist, int* __restrict__ blockBase,
    int* __restrict__ counts, int* __restrict__ offsets) {
    int t = threadIdx.x;
    int c = t >> 6;      // chunk 0..3 (64 hist-blocks each)
    int k = t & 63;
    __shared__ int chunkTot[4][KC];
    __shared__ int kTot[KC];
    int acc = 0;
    for (int b = c * 64; b < c * 64 + 64; ++b) acc += blockHist[b * KC + k];
    chunkTot[c][k] = acc;
    __syncthreads();
    if (c == 0) {
        int tot = chunkTot[0][k] + chunkTot[1][k] + chunkTot[2][k] + chunkTot[3][k];
        kTot[k] = tot;
        counts[k] = tot;
    }
    __syncthreads();
    if (t == 0) {
        int a = 0;
        for (int j = 0; j < KC; ++j) { offsets[j] = a; a += kTot[j]; }
    }
    // within-k running base for this chunk
    int run = 0;
    for (int cc = 0; cc < c; ++cc) run += chunkTot[cc][k];
    for (int b = c * 64; b < c * 64 + 64; ++b) {
        blockBase[b * KC + k] = run;
        run += blockHist[b * KC + k];
    }
}

// ---------------------------------------------------------------------------
// K3: scatter rows into cluster-sorted order. LDS cursors only.
// ---------------------------------------------------------------------------
__global__ __launch_bounds__(64) void k_scatter(
    const int* __restrict__ idx, const int* __restrict__ offsets,
    const int* __restrict__ blockBase, int* __restrict__ order) {
    __shared__ int cur[KC];
    int t = threadIdx.x;
    cur[t] = offsets[t] + blockBase[blockIdx.x * KC + t];
    __syncthreads();
    int n = blockIdx.x * ROWS_PER_HB + t;
    int k = idx[n];
    int p = atomicAdd(&cur[k], 1);
    order[p] = n;
}

// ---------------------------------------------------------------------------
// K4: row_sum[k] = sum_j ||c_k - c_j||^2 ; then inv_denom[k], scale[k].
// ---------------------------------------------------------------------------
__global__ __launch_bounds__(256) void k_rowsum(
    const float* __restrict__ cluster, const float* __restrict__ cw,
    float* __restrict__ inv_denom, float* __restrict__ scale) {
    int k = blockIdx.x, t = threadIdx.x;
    const float4* c4 = (const float4*)cluster;
    float4 a0 = c4[k * F4 + t];
    float4 a1 = c4[k * F4 + 256 + t];
    float acc = 0.f;
    for (int j = 0; j < KC; ++j) {
        float4 b0 = c4[j * F4 + t];
        float4 b1 = c4[j * F4 + 256 + t];
        float d;
        d = a0.x - b0.x; acc += d * d;
        d = a0.y - b0.y; acc += d * d;
        d = a0.z - b0.z; acc += d * d;
        d = a0.w - b0.w; acc += d * d;
        d = a1.x - b1.x; acc += d * d;
        d = a1.y - b1.y; acc += d * d;
        d = a1.z - b1.z; acc += d * d;
        d = a1.w - b1.w; acc += d * d;
    }
    #pragma unroll
    for (int off = 32; off >= 1; off >>= 1) acc += __shfl_down(acc, off);
    __shared__ float red[4];
    if ((t & 63) == 0) red[t >> 6] = acc;
    __syncthreads();
    if (t == 0) {
        float denom = red[0] + red[1] + red[2] + red[3] + ALPHA;
        inv_denom[k] = 1.0f / denom;
        scale[k]     = cw[k] / denom;
    }
}

// ---------------------------------------------------------------------------
// K5: fused main pass. Grid = (NROWS/ROWS)*2 = 2048 blocks (8/CU, 32 waves/CU).
// Block (pair,half) handles 16 sorted rows x 1024 features (1 float4/thread/row).
// Fast path (~94% of blocks): whole block one cluster -> single delta flush.
// ---------------------------------------------------------------------------
__global__ __launch_bounds__(256) void k_main(
    const float* __restrict__ features, const float* __restrict__ cluster,
    const int* __restrict__ idx, const int* __restrict__ order,
    const float* __restrict__ inv_denom, float* __restrict__ delta,
    float* __restrict__ loss) {
    int t = threadIdx.x;
    int pair = blockIdx.x >> 1, half = blockIdx.x & 1;
    int foff = half * 256;                 // float4 offset within the row
    __shared__ float part[ROWS][256];
    __shared__ int onum[ROWS];
    __shared__ int okk[ROWS];
    if (t < ROWS) {
        int n = order[pair * ROWS + t];
        onum[t] = n;
        okk[t]  = idx[n];
    }
    __syncthreads();

    const f32x4* f4 = (const f32x4*)features;
    const f32x4* c4 = (const f32x4*)cluster;
    float4 s = {0.f, 0.f, 0.f, 0.f};
    int k0 = okk[0];

    if (okk[ROWS - 1] == k0) {
        // ---- fast path: one cluster for the whole block ----
        f32x4 cv = c4[k0 * F4 + foff + t];
        for (int r = 0; r < ROWS; r += 4) {
            f32x4 x0 = __builtin_nontemporal_load(&f4[(size_t)onum[r + 0] * F4 + foff + t]);
            f32x4 x1 = __builtin_nontemporal_load(&f4[(size_t)onum[r + 1] * F4 + foff + t]);
            f32x4 x2 = __builtin_nontemporal_load(&f4[(size_t)onum[r + 2] * F4 + foff + t]);
            f32x4 x3 = __builtin_nontemporal_load(&f4[(size_t)onum[r + 3] * F4 + foff + t]);
            float d, p;
            s.x += x0.x; s.y += x0.y; s.z += x0.z; s.w += x0.w;
            p = 0.f;
            d = x0.x - cv.x; p += d * d;
            d = x0.y - cv.y; p += d * d;
            d = x0.z - cv.z; p += d * d;
            d = x0.w - cv.w; p += d * d;
            part[r + 0][t] = p;
            s.x += x1.x; s.y += x1.y; s.z += x1.z; s.w += x1.w;
            p = 0.f;
            d = x1.x - cv.x; p += d * d;
            d = x1.y - cv.y; p += d * d;
            d = x1.z - cv.z; p += d * d;
            d = x1.w - cv.w; p += d * d;
            part[r + 1][t] = p;
            s.x += x2.x; s.y += x2.y; s.z += x2.z; s.w += x2.w;
            p = 0.f;
            d = x2.x - cv.x; p += d * d;
            d = x2.y - cv.y; p += d * d;
            d = x2.z - cv.z; p += d * d;
            d = x2.w - cv.w; p += d * d;
            part[r + 2][t] = p;
            s.x += x3.x; s.y += x3.y; s.z += x3.z; s.w += x3.w;
            p = 0.f;
            d = x3.x - cv.x; p += d * d;
            d = x3.y - cv.y; p += d * d;
            d = x3.z - cv.z; p += d * d;
            d = x3.w - cv.w; p += d * d;
            part[r + 3][t] = p;
        }
        float* dk = delta + k0 * FDIM + half * 1024;
        atomicAdd(&dk[t * 4 + 0], s.x);
        atomicAdd(&dk[t * 4 + 1], s.y);
        atomicAdd(&dk[t * 4 + 2], s.z);
        atomicAdd(&dk[t * 4 + 3], s.w);
    } else {
        // ---- slow path: cluster boundary inside the block ----
        int cur_k = -1;
        f32x4 cv;
        for (int r = 0; r < ROWS; ++r) {
            int k = okk[r];
            if (k != cur_k) {
                if (cur_k >= 0) {
                    float* dk = delta + cur_k * FDIM + half * 1024;
                    atomicAdd(&dk[t * 4 + 0], s.x);
                    atomicAdd(&dk[t * 4 + 1], s.y);
                    atomicAdd(&dk[t * 4 + 2], s.z);
                    atomicAdd(&dk[t * 4 + 3], s.w);
                    s.x = s.y = s.z = s.w = 0.f;
                }
                cv = c4[k * F4 + foff + t];
                cur_k = k;
            }
            f32x4 x = __builtin_nontemporal_load(&f4[(size_t)onum[r] * F4 + foff + t]);
            s.x += x.x; s.y += x.y; s.z += x.z; s.w += x.w;
            float d, p = 0.f;
            d = x.x - cv.x; p += d * d;
            d = x.y - cv.y; p += d * d;
            d = x.z - cv.z; p += d * d;
            d = x.w - cv.w; p += d * d;
            part[r][t] = p;
        }
        float* dk = delta + cur_k * FDIM + half * 1024;
        atomicAdd(&dk[t * 4 + 0], s.x);
        atomicAdd(&dk[t * 4 + 1], s.y);
        atomicAdd(&dk[t * 4 + 2], s.z);
        atomicAdd(&dk[t * 4 + 3], s.w);
    }
    __syncthreads();
    // deferred per-row reductions: wave w handles rows w, w+4, ...
    int w = t >> 6, l = t & 63;
    for (int r = w; r < ROWS; r += 4) {
        float v = part[r][l] + part[r][l + 64] + part[r][l + 128] + part[r][l + 192];
        #pragma unroll
        for (int off = 32; off >= 1; off >>= 1) v += __shfl_down(v, off);
        if (l == 0) {
            atomicAdd(&loss[onum[r]], v * inv_denom[okk[r]]);
        }
    }
}

// ---------------------------------------------------------------------------
// K6: finalize cluster update:
//   new_c[k,f] = c[k,f] - GAMMA * scale[k] * (delta[k,f] - count[k]*c[k,f])
// ---------------------------------------------------------------------------
__global__ __launch_bounds__(256) void k_finalize(
    const float* __restrict__ cluster, const float* __restrict__ delta,
    const int* __restrict__ counts, const float* __restrict__ scale,
    float* __restrict__ outc) {
    int e = blockIdx.x * 256 + threadIdx.x;   // float4 index over KC*F4 = 32768
    int k = e >> 9;                           // / F4
    const float4* c4 = (const float4*)cluster;
    const float4* d4 = (const float4*)delta;
    float4 c = c4[e], d = d4[e];
    float s = scale[k], cnt = (float)counts[k];
    float4 o;
    o.x = c.x - GAMMA * s * (d.x - cnt * c.x);
    o.y = c.y - GAMMA * s * (d.y - cnt * c.y);
    o.z = c.z - GAMMA * s * (d.z - cnt * c.z);
    o.w = c.w - GAMMA * s * (d.w - cnt * c.w);
    ((float4*)outc)[e] = o;
}

extern "C" void kernel_launch(void* const* d_in, const int* in_sizes, int n_in,
                              void* d_out, int out_size, void* d_ws, size_t ws_size,
                              hipStream_t stream) {
    const float* features = (const float*)d_in[0];   // [N, F]
    const float* labels   = (const float*)d_in[1];   // [N, K]
    const float* cluster  = (const float*)d_in[2];   // [K, F]
    const float* cw       = (const float*)d_in[3];   // [K]
    float* loss = (float*)d_out;                     // [N]
    float* outc = (float*)d_out + NROWS;             // [K, F]

    // Workspace layout:
    char*  ws        = (char*)d_ws;
    float* delta     = (float*)ws;                               // KC*FDIM f32 (512 KB) — memset
    int*   counts    = (int*)(ws + (size_t)KC * FDIM * 4);       // 64
    int*   offsets   = counts + KC;                              // 64
    float* inv_denom = (float*)(offsets + KC);                   // 64
    float* scale     = inv_denom + KC;                           // 64
    int*   idx       = (int*)(scale + KC);                       // N
    int*   order     = idx + NROWS;                              // N
    int*   blockHist = order + NROWS;                            // HB*KC = 16384
    int*   blockBase = blockHist + HB * KC;                      // HB*KC = 16384

    // zero delta (accumulator) and loss (atomic target)
    hipMemsetAsync(delta, 0, (size_t)KC * FDIM * 4, stream);
    hipMemsetAsync(loss, 0, (size_t)NROWS * 4, stream);

    k_argmax_hist<<<HB, 256, 0, stream>>>(labels, idx, blockHist);
    k_rowsum<<<KC, 256, 0, stream>>>(cluster, cw, inv_denom, scale);
    k_prefix<<<1, 256, 0, stream>>>(blockHist, blockBase, counts, offsets);
    k_scatter<<<HB, 64, 0, stream>>>(idx, offsets, blockBase, order);
    k_main<<<(NROWS / ROWS) * 2, 256, 0, stream>>>(features, cluster, idx, order,
                                                   inv_denom, delta, loss);
    k_finalize<<<(KC * F4) / 256, 256, 0, stream>>>(cluster, delta, counts, scale, outc);
}

// Round 5
// 224.524 us; speedup vs baseline: 1.0591x; 1.0591x over previous
//
#include <hip/hip_runtime.h>

// Problem constants (fixed by the reference): N=16384 rows, K=64 clusters, F=2048 features.
#define NROWS 16384
#define KC 64
#define FDIM 2048
#define F4 (FDIM / 4)   // 512 float4 per row
#define ALPHA 1.0f
#define GAMMA 1.0f
#define ROWS 16                  // rows per k_main row-group
#define HB 128                   // histogram blocks
#define ROWS_PER_HB 128          // rows per histogram/scatter block

typedef float f32x4 __attribute__((ext_vector_type(4)));

// ---------------------------------------------------------------------------
// K1: ballot-based argmax of one-hot labels + per-block LDS histogram.
// Also zeroes delta[] (128 blocks x 256 thr x 1 float4 = 512 KB exactly).
// ---------------------------------------------------------------------------
__global__ __launch_bounds__(256) void k_argmax_hist(
    const float* __restrict__ labels, int* __restrict__ idx,
    int* __restrict__ blockHist, float4* __restrict__ delta4) {
    __shared__ int hist[KC];
    int t = threadIdx.x, w = t >> 6, lane = t & 63;
    if (t < KC) hist[t] = 0;
    float4 z = {0.f, 0.f, 0.f, 0.f};
    delta4[blockIdx.x * 256 + t] = z;      // zero the delta accumulator
    __syncthreads();
    int rowbase = blockIdx.x * ROWS_PER_HB + w * 32;
    #pragma unroll
    for (int r0 = 0; r0 < 32; r0 += 4) {
        float v0 = labels[(rowbase + r0 + 0) * KC + lane];
        float v1 = labels[(rowbase + r0 + 1) * KC + lane];
        float v2 = labels[(rowbase + r0 + 2) * KC + lane];
        float v3 = labels[(rowbase + r0 + 3) * KC + lane];
        unsigned long long m0 = __ballot(v0 > 0.5f);
        unsigned long long m1 = __ballot(v1 > 0.5f);
        unsigned long long m2 = __ballot(v2 > 0.5f);
        unsigned long long m3 = __ballot(v3 > 0.5f);
        if (lane == 0) {
            int k0 = __ffsll(m0) - 1;
            int k1 = __ffsll(m1) - 1;
            int k2 = __ffsll(m2) - 1;
            int k3 = __ffsll(m3) - 1;
            idx[rowbase + r0 + 0] = k0;
            idx[rowbase + r0 + 1] = k1;
            idx[rowbase + r0 + 2] = k2;
            idx[rowbase + r0 + 3] = k3;
            atomicAdd(&hist[k0], 1);
            atomicAdd(&hist[k1], 1);
            atomicAdd(&hist[k2], 1);
            atomicAdd(&hist[k3], 1);
        }
    }
    __syncthreads();
    if (t < KC) blockHist[blockIdx.x * KC + t] = hist[t];
}

// ---------------------------------------------------------------------------
// K2: fused. Block 0: prefix sums (blockBase per hist-block, counts, offsets).
// Blocks 1..64: rowsum for cluster k = blockIdx-1 -> inv_denom[k], scale[k].
// ---------------------------------------------------------------------------
__global__ __launch_bounds__(256) void k_prefix_rowsum(
    const int* __restrict__ blockHist, int* __restrict__ blockBase,
    int* __restrict__ counts, int* __restrict__ offsets,
    const float* __restrict__ cluster, const float* __restrict__ cw,
    float* __restrict__ inv_denom, float* __restrict__ scale) {
    if (blockIdx.x == 0) {
        // ---- prefix: 256 threads = 4 chunks x 64 k, 32 hist-blocks/chunk ----
        int t = threadIdx.x, c = t >> 6, k = t & 63;
        __shared__ int chunkTot[4][KC];
        __shared__ int kTot[KC];
        int acc = 0;
        for (int b = c * 32; b < c * 32 + 32; ++b) acc += blockHist[b * KC + k];
        chunkTot[c][k] = acc;
        __syncthreads();
        if (c == 0) {
            int tot = chunkTot[0][k] + chunkTot[1][k] + chunkTot[2][k] + chunkTot[3][k];
            kTot[k] = tot;
            counts[k] = tot;
        }
        __syncthreads();
        if (t == 0) {
            int a = 0;
            for (int j = 0; j < KC; ++j) { offsets[j] = a; a += kTot[j]; }
        }
        int run = 0;
        for (int cc = 0; cc < c; ++cc) run += chunkTot[cc][k];
        for (int b = c * 32; b < c * 32 + 32; ++b) {
            blockBase[b * KC + k] = run;
            run += blockHist[b * KC + k];
        }
    } else {
        // ---- rowsum for cluster k ----
        int k = blockIdx.x - 1, t = threadIdx.x;
        const float4* c4 = (const float4*)cluster;
        float4 a0 = c4[k * F4 + t];
        float4 a1 = c4[k * F4 + 256 + t];
        float acc = 0.f;
        for (int j = 0; j < KC; ++j) {
            float4 b0 = c4[j * F4 + t];
            float4 b1 = c4[j * F4 + 256 + t];
            float d;
            d = a0.x - b0.x; acc += d * d;
            d = a0.y - b0.y; acc += d * d;
            d = a0.z - b0.z; acc += d * d;
            d = a0.w - b0.w; acc += d * d;
            d = a1.x - b1.x; acc += d * d;
            d = a1.y - b1.y; acc += d * d;
            d = a1.z - b1.z; acc += d * d;
            d = a1.w - b1.w; acc += d * d;
        }
        #pragma unroll
        for (int off = 32; off >= 1; off >>= 1) acc += __shfl_down(acc, off);
        __shared__ float red[4];
        if ((t & 63) == 0) red[t >> 6] = acc;
        __syncthreads();
        if (t == 0) {
            float denom = red[0] + red[1] + red[2] + red[3] + ALPHA;
            inv_denom[k] = 1.0f / denom;
            scale[k]     = cw[k] / denom;
        }
    }
}

// ---------------------------------------------------------------------------
// K3: scatter rows into cluster-sorted order. LDS cursors only.
// ---------------------------------------------------------------------------
__global__ __launch_bounds__(128) void k_scatter(
    const int* __restrict__ idx, const int* __restrict__ offsets,
    const int* __restrict__ blockBase, int* __restrict__ order) {
    __shared__ int cur[KC];
    int t = threadIdx.x;
    if (t < KC) cur[t] = offsets[t] + blockBase[blockIdx.x * KC + t];
    __syncthreads();
    int n = blockIdx.x * ROWS_PER_HB + t;
    int k = idx[n];
    int p = atomicAdd(&cur[k], 1);
    order[p] = n;
}

// ---------------------------------------------------------------------------
// K4: fused main pass. Grid = (NROWS/ROWS)*2 = 2048 blocks (8/CU, 32 waves/CU).
// Block (pair,half) handles 16 sorted rows x 1024 features (1 float4/thread/row).
// Fast path (~94% of blocks): whole block one cluster -> single delta flush.
// Loss partials go to lossPart[half*N + n] with plain stores (no atomics).
// ---------------------------------------------------------------------------
__global__ __launch_bounds__(256) void k_main(
    const float* __restrict__ features, const float* __restrict__ cluster,
    const int* __restrict__ idx, const int* __restrict__ order,
    const float* __restrict__ inv_denom, float* __restrict__ delta,
    float* __restrict__ lossPart) {
    int t = threadIdx.x;
    int pair = blockIdx.x >> 1, half = blockIdx.x & 1;
    int foff = half * 256;                 // float4 offset within the row
    __shared__ float part[ROWS][256];
    __shared__ int onum[ROWS];
    __shared__ int okk[ROWS];
    if (t < ROWS) {
        int n = order[pair * ROWS + t];
        onum[t] = n;
        okk[t]  = idx[n];
    }
    __syncthreads();

    const f32x4* f4 = (const f32x4*)features;
    const f32x4* c4 = (const f32x4*)cluster;
    float4 s = {0.f, 0.f, 0.f, 0.f};
    int k0 = okk[0];

    if (okk[ROWS - 1] == k0) {
        // ---- fast path: one cluster for the whole block ----
        f32x4 cv = c4[k0 * F4 + foff + t];
        for (int r = 0; r < ROWS; r += 4) {
            f32x4 x0 = __builtin_nontemporal_load(&f4[(size_t)onum[r + 0] * F4 + foff + t]);
            f32x4 x1 = __builtin_nontemporal_load(&f4[(size_t)onum[r + 1] * F4 + foff + t]);
            f32x4 x2 = __builtin_nontemporal_load(&f4[(size_t)onum[r + 2] * F4 + foff + t]);
            f32x4 x3 = __builtin_nontemporal_load(&f4[(size_t)onum[r + 3] * F4 + foff + t]);
            float d, p;
            s.x += x0.x; s.y += x0.y; s.z += x0.z; s.w += x0.w;
            p = 0.f;
            d = x0.x - cv.x; p += d * d;
            d = x0.y - cv.y; p += d * d;
            d = x0.z - cv.z; p += d * d;
            d = x0.w - cv.w; p += d * d;
            part[r + 0][t] = p;
            s.x += x1.x; s.y += x1.y; s.z += x1.z; s.w += x1.w;
            p = 0.f;
            d = x1.x - cv.x; p += d * d;
            d = x1.y - cv.y; p += d * d;
            d = x1.z - cv.z; p += d * d;
            d = x1.w - cv.w; p += d * d;
            part[r + 1][t] = p;
            s.x += x2.x; s.y += x2.y; s.z += x2.z; s.w += x2.w;
            p = 0.f;
            d = x2.x - cv.x; p += d * d;
            d = x2.y - cv.y; p += d * d;
            d = x2.z - cv.z; p += d * d;
            d = x2.w - cv.w; p += d * d;
            part[r + 2][t] = p;
            s.x += x3.x; s.y += x3.y; s.z += x3.z; s.w += x3.w;
            p = 0.f;
            d = x3.x - cv.x; p += d * d;
            d = x3.y - cv.y; p += d * d;
            d = x3.z - cv.z; p += d * d;
            d = x3.w - cv.w; p += d * d;
            part[r + 3][t] = p;
        }
        float* dk = delta + k0 * FDIM + half * 1024;
        atomicAdd(&dk[t * 4 + 0], s.x);
        atomicAdd(&dk[t * 4 + 1], s.y);
        atomicAdd(&dk[t * 4 + 2], s.z);
        atomicAdd(&dk[t * 4 + 3], s.w);
    } else {
        // ---- slow path: cluster boundary inside the block ----
        int cur_k = -1;
        f32x4 cv;
        for (int r = 0; r < ROWS; ++r) {
            int k = okk[r];
            if (k != cur_k) {
                if (cur_k >= 0) {
                    float* dk = delta + cur_k * FDIM + half * 1024;
                    atomicAdd(&dk[t * 4 + 0], s.x);
                    atomicAdd(&dk[t * 4 + 1], s.y);
                    atomicAdd(&dk[t * 4 + 2], s.z);
                    atomicAdd(&dk[t * 4 + 3], s.w);
                    s.x = s.y = s.z = s.w = 0.f;
                }
                cv = c4[k * F4 + foff + t];
                cur_k = k;
            }
            f32x4 x = __builtin_nontemporal_load(&f4[(size_t)onum[r] * F4 + foff + t]);
            s.x += x.x; s.y += x.y; s.z += x.z; s.w += x.w;
            float d, p = 0.f;
            d = x.x - cv.x; p += d * d;
            d = x.y - cv.y; p += d * d;
            d = x.z - cv.z; p += d * d;
            d = x.w - cv.w; p += d * d;
            part[r][t] = p;
        }
        float* dk = delta + cur_k * FDIM + half * 1024;
        atomicAdd(&dk[t * 4 + 0], s.x);
        atomicAdd(&dk[t * 4 + 1], s.y);
        atomicAdd(&dk[t * 4 + 2], s.z);
        atomicAdd(&dk[t * 4 + 3], s.w);
    }
    __syncthreads();
    // deferred per-row reductions: wave w handles rows w, w+4, ...
    int w = t >> 6, l = t & 63;
    for (int r = w; r < ROWS; r += 4) {
        float v = part[r][l] + part[r][l + 64] + part[r][l + 128] + part[r][l + 192];
        #pragma unroll
        for (int off = 32; off >= 1; off >>= 1) v += __shfl_down(v, off);
        if (l == 0) {
            lossPart[half * NROWS + onum[r]] = v * inv_denom[okk[r]];
        }
    }
}

// ---------------------------------------------------------------------------
// K5: finalize. Blocks 0..127: cluster update. Blocks 128..191: loss = sum of
// the two feature-half partials.
// ---------------------------------------------------------------------------
__global__ __launch_bounds__(256) void k_finalize(
    const float* __restrict__ cluster, const float* __restrict__ delta,
    const int* __restrict__ counts, const float* __restrict__ scale,
    const float* __restrict__ lossPart, float* __restrict__ outc,
    float* __restrict__ loss) {
    int b = blockIdx.x, t = threadIdx.x;
    if (b < 128) {
        int e = b * 256 + t;                  // float4 index over KC*F4 = 32768
        int k = e >> 9;                       // / F4
        const float4* c4 = (const float4*)cluster;
        const float4* d4 = (const float4*)delta;
        float4 c = c4[e], d = d4[e];
        float s = scale[k], cnt = (float)counts[k];
        float4 o;
        o.x = c.x - GAMMA * s * (d.x - cnt * c.x);
        o.y = c.y - GAMMA * s * (d.y - cnt * c.y);
        o.z = c.z - GAMMA * s * (d.z - cnt * c.z);
        o.w = c.w - GAMMA * s * (d.w - cnt * c.w);
        ((float4*)outc)[e] = o;
    } else {
        int n = (b - 128) * 256 + t;          // 64 blocks x 256 = 16384
        loss[n] = lossPart[n] + lossPart[NROWS + n];
    }
}

extern "C" void kernel_launch(void* const* d_in, const int* in_sizes, int n_in,
                              void* d_out, int out_size, void* d_ws, size_t ws_size,
                              hipStream_t stream) {
    const float* features = (const float*)d_in[0];   // [N, F]
    const float* labels   = (const float*)d_in[1];   // [N, K]
    const float* cluster  = (const float*)d_in[2];   // [K, F]
    const float* cw       = (const float*)d_in[3];   // [K]
    float* loss = (float*)d_out;                     // [N]
    float* outc = (float*)d_out + NROWS;             // [K, F]

    // Workspace layout:
    char*  ws        = (char*)d_ws;
    float* delta     = (float*)ws;                               // KC*FDIM f32 (512 KB)
    int*   counts    = (int*)(ws + (size_t)KC * FDIM * 4);       // 64
    int*   offsets   = counts + KC;                              // 64
    float* inv_denom = (float*)(offsets + KC);                   // 64
    float* scale     = inv_denom + KC;                           // 64
    int*   idx       = (int*)(scale + KC);                       // N
    int*   order     = idx + NROWS;                              // N
    int*   blockHist = order + NROWS;                            // HB*KC = 8192
    int*   blockBase = blockHist + HB * KC;                      // HB*KC = 8192
    float* lossPart  = (float*)(blockBase + HB * KC);            // 2*N

    k_argmax_hist<<<HB, 256, 0, stream>>>(labels, idx, blockHist, (float4*)delta);
    k_prefix_rowsum<<<KC + 1, 256, 0, stream>>>(blockHist, blockBase, counts, offsets,
                                                cluster, cw, inv_denom, scale);
    k_scatter<<<HB, 128, 0, stream>>>(idx, offsets, blockBase, order);
    k_main<<<(NROWS / ROWS) * 2, 256, 0, stream>>>(features, cluster, idx, order,
                                                   inv_denom, delta, lossPart);
    k_finalize<<<192, 256, 0, stream>>>(cluster, delta, counts, scale, lossPart,
                                        outc, loss);
}